// Round 1
// baseline (867.207 us; speedup 1.0000x reference)
//
#include <hip/hip_runtime.h>

#define N_NODES 100000
#define N_EDGES 1600000
#define IN_DIM  128
#define OUT_DIM 64
#define HEADS   4
#define SLOPE   0.2f
#define CLIP_LO 0.005f
#define CLIP_HI 10.0f

// ---------------------------------------------------------------------------
// Kernel A: Wa[k][half][i] = sum_j W[k][i][j] * a[k][half*64 + j]
// (s_src = hw @ a1 = h @ (W @ a1) -> fold attention vector through W)
// ---------------------------------------------------------------------------
__global__ void wa_kernel(const float* __restrict__ W, const float* __restrict__ a,
                          float* __restrict__ Wa) {
    int o = blockIdx.x * blockDim.x + threadIdx.x;   // 0..1023
    if (o >= HEADS * 2 * IN_DIM) return;
    int k    = o >> 8;          // /256
    int half = (o >> 7) & 1;    // /128 % 2
    int i    = o & 127;
    const float* wrow = W + ((size_t)k * IN_DIM + i) * OUT_DIM;
    const float* av   = a + k * 2 * OUT_DIM + half * OUT_DIM;
    float acc = 0.f;
#pragma unroll 8
    for (int j = 0; j < OUT_DIM; ++j) acc += wrow[j] * av[j];
    Wa[o] = acc;   // layout [k][half][i]
}

// ---------------------------------------------------------------------------
// Kernel B: per-node scores sArr[n][0..3] = h[n]·Wa[k,src], [4..7] = h[n]·Wa[k,dst]
// ---------------------------------------------------------------------------
__global__ __launch_bounds__(256) void s_kernel(const float* __restrict__ h,
                                                const float* __restrict__ Wa,
                                                float* __restrict__ sArr) {
    __shared__ __align__(16) float wa_s[HEADS * 2 * IN_DIM];   // 4KB
    for (int t = threadIdx.x; t < HEADS * 2 * IN_DIM; t += 256) wa_s[t] = Wa[t];
    __syncthreads();
    int n = blockIdx.x * 256 + threadIdx.x;
    if (n >= N_NODES) return;
    const float4* hv = (const float4*)(h + (size_t)n * IN_DIM);
    const float4* wv = (const float4*)wa_s;
    float acc[8] = {0.f,0.f,0.f,0.f,0.f,0.f,0.f,0.f};
    for (int i4 = 0; i4 < IN_DIM / 4; ++i4) {
        float4 hx = hv[i4];
#pragma unroll
        for (int k2 = 0; k2 < 8; ++k2) {
            float4 w = wv[k2 * (IN_DIM / 4) + i4];
            acc[k2] += hx.x * w.x + hx.y * w.y + hx.z * w.z + hx.w * w.w;
        }
    }
    float* o = sArr + (size_t)n * 8;
    // acc index = k*2 + half ; want [k] = src(half0), [4+k] = dst(half1)
#pragma unroll
    for (int k = 0; k < 4; ++k) { o[k] = acc[2 * k]; o[4 + k] = acc[2 * k + 1]; }
}

// ---------------------------------------------------------------------------
// Kernel C: hw[k][n][j] = sum_i h[n][i] * W[k][i][j]
// BM=64 rows, BN=64 (one head), K=128 fully resident in LDS. 256 thr, 4x4 microtile.
// ---------------------------------------------------------------------------
__global__ __launch_bounds__(256) void gemm_kernel(const float* __restrict__ h,
                                                   const float* __restrict__ W,
                                                   float* __restrict__ hw) {
    __shared__ float As[64][128];   // 32KB
    __shared__ float Bs[128][64];   // 32KB
    const int k    = blockIdx.y;
    const int row0 = blockIdx.x * 64;
    const int tid  = threadIdx.x;

    // stage A (64x128), 8 float4 per thread, coalesced
#pragma unroll
    for (int t = 0; t < 8; ++t) {
        int idx = tid + t * 256;          // 0..2047
        int r = idx >> 5, c4 = idx & 31;
        float4 v = make_float4(0.f, 0.f, 0.f, 0.f);
        int grow = row0 + r;
        if (grow < N_NODES) v = *(const float4*)(h + (size_t)grow * IN_DIM + c4 * 4);
        *(float4*)&As[r][c4 * 4] = v;
    }
    // stage B = W[k] (128x64)
    const float* Wk = W + (size_t)k * IN_DIM * OUT_DIM;
#pragma unroll
    for (int t = 0; t < 8; ++t) {
        int idx = tid + t * 256;          // 0..2047
        int r = idx >> 4, c4 = idx & 15;
        *(float4*)&Bs[r][c4 * 4] = *(const float4*)(Wk + (size_t)r * 64 + c4 * 4);
    }
    __syncthreads();

    const int ty = tid >> 4, tx = tid & 15;   // rows ty*4..+3, cols tx*4..+3
    float acc[4][4] = {};
    for (int i4 = 0; i4 < 32; ++i4) {
        float4 av[4];
#pragma unroll
        for (int u = 0; u < 4; ++u) av[u] = *(const float4*)&As[ty * 4 + u][i4 * 4];
        float4 bv0 = *(const float4*)&Bs[i4 * 4 + 0][tx * 4];
        float4 bv1 = *(const float4*)&Bs[i4 * 4 + 1][tx * 4];
        float4 bv2 = *(const float4*)&Bs[i4 * 4 + 2][tx * 4];
        float4 bv3 = *(const float4*)&Bs[i4 * 4 + 3][tx * 4];
#pragma unroll
        for (int u = 0; u < 4; ++u) {
            float4 A4 = av[u];
            acc[u][0] += A4.x * bv0.x + A4.y * bv1.x + A4.z * bv2.x + A4.w * bv3.x;
            acc[u][1] += A4.x * bv0.y + A4.y * bv1.y + A4.z * bv2.y + A4.w * bv3.y;
            acc[u][2] += A4.x * bv0.z + A4.y * bv1.z + A4.z * bv2.z + A4.w * bv3.z;
            acc[u][3] += A4.x * bv0.w + A4.y * bv1.w + A4.z * bv2.w + A4.w * bv3.w;
        }
    }
#pragma unroll
    for (int u = 0; u < 4; ++u) {
        int g = row0 + ty * 4 + u;
        if (g < N_NODES) {
            float4 v = make_float4(acc[u][0], acc[u][1], acc[u][2], acc[u][3]);
            *(float4*)(hw + (size_t)k * N_NODES * OUT_DIM + (size_t)g * OUT_DIM + tx * 4) = v;
        }
    }
}

// ---------------------------------------------------------------------------
__device__ __forceinline__ float edge_e(float x) {
    x = x > 0.f ? x : SLOPE * x;
    float ev = __expf(x);
    return fminf(fmaxf(ev, CLIP_LO), CLIP_HI);
}

// Kernel D: denom[d][k] += e(edge)  — one thread per edge
__global__ __launch_bounds__(256) void denom_kernel(const int* __restrict__ edges,
                                                    const float* __restrict__ sArr,
                                                    float* __restrict__ denom) {
    int e = blockIdx.x * blockDim.x + threadIdx.x;
    if (e >= N_EDGES) return;
    int s = edges[e], d = edges[N_EDGES + e];
    float4 ss = *(const float4*)(sArr + (size_t)s * 8);
    float4 sd = *(const float4*)(sArr + (size_t)d * 8 + 4);
    atomicAdd(denom + (size_t)d * 4 + 0, edge_e(ss.x + sd.x));
    atomicAdd(denom + (size_t)d * 4 + 1, edge_e(ss.y + sd.y));
    atomicAdd(denom + (size_t)d * 4 + 2, edge_e(ss.z + sd.z));
    atomicAdd(denom + (size_t)d * 4 + 3, edge_e(ss.w + sd.w));
}

// Kernel E: out[d][j] += sum_k 0.25 * (e_k/denom_k[d]) * hw[k][s][j]
// one WAVE per edge, lane j = output dim; one atomic per (edge, j)
__global__ __launch_bounds__(256) void msg_kernel(const int* __restrict__ edges,
                                                  const float* __restrict__ sArr,
                                                  const float* __restrict__ denom,
                                                  const float* __restrict__ hw,
                                                  float* __restrict__ out) {
    const int lane = threadIdx.x & 63;
    int wid = (blockIdx.x * 256 + threadIdx.x) >> 6;
    const int nw = (gridDim.x * 256) >> 6;
    for (int e = wid; e < N_EDGES; e += nw) {
        int s = edges[e], d = edges[N_EDGES + e];
        float4 ss  = *(const float4*)(sArr + (size_t)s * 8);
        float4 sd  = *(const float4*)(sArr + (size_t)d * 8 + 4);
        float4 den = *(const float4*)(denom + (size_t)d * 4);
        float w0 = edge_e(ss.x + sd.x) * 0.25f / den.x;
        float w1 = edge_e(ss.y + sd.y) * 0.25f / den.y;
        float w2 = edge_e(ss.z + sd.z) * 0.25f / den.z;
        float w3 = edge_e(ss.w + sd.w) * 0.25f / den.w;
        const float* hs = hw + (size_t)s * OUT_DIM + lane;
        const size_t HS = (size_t)N_NODES * OUT_DIM;
        float m = w0 * hs[0] + w1 * hs[HS] + w2 * hs[2 * HS] + w3 * hs[3 * HS];
        atomicAdd(out + (size_t)d * OUT_DIM + lane, m);
    }
}

// ---------------------------------------------------------------------------
extern "C" void kernel_launch(void* const* d_in, const int* in_sizes, int n_in,
                              void* d_out, int out_size, void* d_ws, size_t ws_size,
                              hipStream_t stream) {
    const float* h     = (const float*)d_in[0];
    const int*   edges = (const int*)d_in[1];
    const float* W     = (const float*)d_in[2];
    const float* a     = (const float*)d_in[3];
    float* out = (float*)d_out;

    char* ws = (char*)d_ws;
    float* hw    = (float*)(ws);                          // 4*N*64 f32 = 102,400,000 B
    float* sArr  = (float*)(ws + 102400000);              // N*8 f32   =   3,200,000 B
    float* denom = (float*)(ws + 105600000);              // N*4 f32   =   1,600,000 B
    float* Wa    = (float*)(ws + 107200000);              // 1024 f32

    hipMemsetAsync(out, 0, (size_t)out_size * sizeof(float), stream);
    hipMemsetAsync(denom, 0, (size_t)N_NODES * HEADS * sizeof(float), stream);

    wa_kernel<<<4, 256, 0, stream>>>(W, a, Wa);
    s_kernel<<<(N_NODES + 255) / 256, 256, 0, stream>>>(h, Wa, sArr);
    gemm_kernel<<<dim3((N_NODES + 63) / 64, HEADS), 256, 0, stream>>>(h, W, hw);
    denom_kernel<<<(N_EDGES + 255) / 256, 256, 0, stream>>>(edges, sArr, denom);
    msg_kernel<<<2048, 256, 0, stream>>>(edges, sArr, denom, hw, out);
}

// Round 2
// 524.625 us; speedup vs baseline: 1.6530x; 1.6530x over previous
//
#include <hip/hip_runtime.h>

#define N_NODES 100000
#define N_EDGES 1600000
#define IN_DIM  128
#define OUT_DIM 64
#define HEADS   4
#define SLOPE   0.2f
#define CLIP_LO 0.005f
#define CLIP_HI 10.0f

// ---------------------------------------------------------------------------
// Kernel A: Wa[k][half][i] = sum_j W[k][i][j] * a[k][half*64 + j]
// ---------------------------------------------------------------------------
__global__ void wa_kernel(const float* __restrict__ W, const float* __restrict__ a,
                          float* __restrict__ Wa) {
    int o = blockIdx.x * blockDim.x + threadIdx.x;   // 0..1023
    if (o >= HEADS * 2 * IN_DIM) return;
    int k    = o >> 8;
    int half = (o >> 7) & 1;
    int i    = o & 127;
    const float* wrow = W + ((size_t)k * IN_DIM + i) * OUT_DIM;
    const float* av   = a + k * 2 * OUT_DIM + half * OUT_DIM;
    float acc = 0.f;
#pragma unroll 8
    for (int j = 0; j < OUT_DIM; ++j) acc += wrow[j] * av[j];
    Wa[o] = acc;   // layout [k][half][i]
}

// ---------------------------------------------------------------------------
// Kernel B: per-node scores sArr[n][0..3]=h[n]·Wa[k,src], [4..7]=h[n]·Wa[k,dst]
// ---------------------------------------------------------------------------
__global__ __launch_bounds__(256) void s_kernel(const float* __restrict__ h,
                                                const float* __restrict__ Wa,
                                                float* __restrict__ sArr) {
    __shared__ __align__(16) float wa_s[HEADS * 2 * IN_DIM];
    for (int t = threadIdx.x; t < HEADS * 2 * IN_DIM; t += 256) wa_s[t] = Wa[t];
    __syncthreads();
    int n = blockIdx.x * 256 + threadIdx.x;
    if (n >= N_NODES) return;
    const float4* hv = (const float4*)(h + (size_t)n * IN_DIM);
    const float4* wv = (const float4*)wa_s;
    float acc[8] = {0.f,0.f,0.f,0.f,0.f,0.f,0.f,0.f};
    for (int i4 = 0; i4 < IN_DIM / 4; ++i4) {
        float4 hx = hv[i4];
#pragma unroll
        for (int k2 = 0; k2 < 8; ++k2) {
            float4 w = wv[k2 * (IN_DIM / 4) + i4];
            acc[k2] += hx.x * w.x + hx.y * w.y + hx.z * w.z + hx.w * w.w;
        }
    }
    float* o = sArr + (size_t)n * 8;
#pragma unroll
    for (int k = 0; k < 4; ++k) { o[k] = acc[2 * k]; o[4 + k] = acc[2 * k + 1]; }
}

// ---------------------------------------------------------------------------
// Kernel C: hw[n][k*64+j] = sum_i h[n][i] * W[k][i][j]   (node-major layout!)
// ---------------------------------------------------------------------------
__global__ __launch_bounds__(256) void gemm_kernel(const float* __restrict__ h,
                                                   const float* __restrict__ W,
                                                   float* __restrict__ hw) {
    __shared__ float As[64][128];
    __shared__ float Bs[128][64];
    const int k    = blockIdx.y;
    const int row0 = blockIdx.x * 64;
    const int tid  = threadIdx.x;

#pragma unroll
    for (int t = 0; t < 8; ++t) {
        int idx = tid + t * 256;
        int r = idx >> 5, c4 = idx & 31;
        float4 v = make_float4(0.f, 0.f, 0.f, 0.f);
        int grow = row0 + r;
        if (grow < N_NODES) v = *(const float4*)(h + (size_t)grow * IN_DIM + c4 * 4);
        *(float4*)&As[r][c4 * 4] = v;
    }
    const float* Wk = W + (size_t)k * IN_DIM * OUT_DIM;
#pragma unroll
    for (int t = 0; t < 8; ++t) {
        int idx = tid + t * 256;
        int r = idx >> 4, c4 = idx & 15;
        *(float4*)&Bs[r][c4 * 4] = *(const float4*)(Wk + (size_t)r * 64 + c4 * 4);
    }
    __syncthreads();

    const int ty = tid >> 4, tx = tid & 15;
    float acc[4][4] = {};
    for (int i4 = 0; i4 < 32; ++i4) {
        float4 av[4];
#pragma unroll
        for (int u = 0; u < 4; ++u) av[u] = *(const float4*)&As[ty * 4 + u][i4 * 4];
        float4 bv0 = *(const float4*)&Bs[i4 * 4 + 0][tx * 4];
        float4 bv1 = *(const float4*)&Bs[i4 * 4 + 1][tx * 4];
        float4 bv2 = *(const float4*)&Bs[i4 * 4 + 2][tx * 4];
        float4 bv3 = *(const float4*)&Bs[i4 * 4 + 3][tx * 4];
#pragma unroll
        for (int u = 0; u < 4; ++u) {
            float4 A4 = av[u];
            acc[u][0] += A4.x * bv0.x + A4.y * bv1.x + A4.z * bv2.x + A4.w * bv3.x;
            acc[u][1] += A4.x * bv0.y + A4.y * bv1.y + A4.z * bv2.y + A4.w * bv3.y;
            acc[u][2] += A4.x * bv0.z + A4.y * bv1.z + A4.z * bv2.z + A4.w * bv3.z;
            acc[u][3] += A4.x * bv0.w + A4.y * bv1.w + A4.z * bv2.w + A4.w * bv3.w;
        }
    }
#pragma unroll
    for (int u = 0; u < 4; ++u) {
        int g = row0 + ty * 4 + u;
        if (g < N_NODES) {
            float4 v = make_float4(acc[u][0], acc[u][1], acc[u][2], acc[u][3]);
            // node-major: [n][k*64 + j]
            *(float4*)(hw + ((size_t)g * HEADS + k) * OUT_DIM + tx * 4) = v;
        }
    }
}

// ---------------------------------------------------------------------------
__device__ __forceinline__ float edge_e(float x) {
    x = x > 0.f ? x : SLOPE * x;
    float ev = __expf(x);
    return fminf(fmaxf(ev, CLIP_LO), CLIP_HI);
}

// Kernel D1: degree histogram
__global__ __launch_bounds__(256) void deg_hist(const int* __restrict__ edges,
                                                int* __restrict__ deg) {
    int e = blockIdx.x * 256 + threadIdx.x;
    if (e >= N_EDGES) return;
    atomicAdd(&deg[edges[N_EDGES + e]], 1);
}

// Kernel D2: per-1024-chunk block sums of deg
__global__ __launch_bounds__(256) void deg_blocksum(const int* __restrict__ deg,
                                                    int* __restrict__ partial) {
    __shared__ int red[256];
    int base = blockIdx.x * 1024 + threadIdx.x * 4;
    int s = 0;
#pragma unroll
    for (int u = 0; u < 4; ++u) { int i = base + u; if (i < N_NODES) s += deg[i]; }
    red[threadIdx.x] = s; __syncthreads();
    for (int off = 128; off > 0; off >>= 1) {
        if (threadIdx.x < off) red[threadIdx.x] += red[threadIdx.x + off];
        __syncthreads();
    }
    if (threadIdx.x == 0) partial[blockIdx.x] = red[0];
}

// Kernel D3: exclusive scan of partials (nb <= 128, single block)
__global__ __launch_bounds__(128) void scan_partials(int* __restrict__ partial, int nb) {
    __shared__ int sm[128];
    int t = threadIdx.x;
    sm[t] = (t < nb) ? partial[t] : 0;
    __syncthreads();
    if (t == 0) {
        int run = 0;
        for (int i = 0; i < nb; ++i) { int v = sm[i]; sm[i] = run; run += v; }
    }
    __syncthreads();
    if (t < nb) partial[t] = sm[t];
}

// Kernel D4: write row_off (exclusive scan of deg) and cursor copy
__global__ __launch_bounds__(256) void deg_scan_write(const int* __restrict__ deg,
                                                      const int* __restrict__ partial,
                                                      int* __restrict__ row_off,
                                                      int* __restrict__ cursor) {
    __shared__ int sc[2][256];
    int t = threadIdx.x;
    int base = blockIdx.x * 1024 + t * 4;
    int v[4]; int s = 0;
#pragma unroll
    for (int u = 0; u < 4; ++u) { int i = base + u; v[u] = (i < N_NODES) ? deg[i] : 0; s += v[u]; }
    sc[0][t] = s; __syncthreads();
    int cur = 0;
    for (int off = 1; off < 256; off <<= 1) {
        int x = sc[cur][t];
        if (t >= off) x += sc[cur][t - off];
        sc[cur ^ 1][t] = x; __syncthreads(); cur ^= 1;
    }
    int excl = sc[cur][t] - s;
    int run = partial[blockIdx.x] + excl;
#pragma unroll
    for (int u = 0; u < 4; ++u) {
        int i = base + u;
        if (i < N_NODES) { row_off[i] = run; cursor[i] = run; run += v[u]; }
    }
}

// Kernel D5: scatter edges into CSR slots, precomputing clipped-exp weights
__global__ __launch_bounds__(256) void scatter_kernel(const int* __restrict__ edges,
                                                      const float* __restrict__ sArr,
                                                      int* __restrict__ cursor,
                                                      int* __restrict__ csr_src,
                                                      float4* __restrict__ csr_w) {
    int e = blockIdx.x * 256 + threadIdx.x;
    if (e >= N_EDGES) return;
    int s = edges[e], d = edges[N_EDGES + e];
    float4 ss = *(const float4*)(sArr + (size_t)s * 8);
    float4 sd = *(const float4*)(sArr + (size_t)d * 8 + 4);
    float4 w;
    w.x = edge_e(ss.x + sd.x);
    w.y = edge_e(ss.y + sd.y);
    w.z = edge_e(ss.z + sd.z);
    w.w = edge_e(ss.w + sd.w);
    int pos = atomicAdd(&cursor[d], 1);
    csr_src[pos] = s;
    csr_w[pos]   = w;
}

// ---------------------------------------------------------------------------
// Kernel E: one wave per dst node. Pass1: denom from csr_w (lane-parallel +
// shuffle reduce). Pass2: gather hw[src] (1 dwordx4/lane = whole 1KB node),
// accumulate, cross-head reduce, single coalesced store. ZERO atomics.
// ---------------------------------------------------------------------------
__global__ __launch_bounds__(256) void msg_csr(const int* __restrict__ row_off,
                                               const int* __restrict__ deg,
                                               const int* __restrict__ csr_src,
                                               const float4* __restrict__ csr_w,
                                               const float* __restrict__ hw,
                                               float* __restrict__ out) {
    int wid  = (blockIdx.x * 256 + threadIdx.x) >> 6;
    int lane = threadIdx.x & 63;
    if (wid >= N_NODES) return;
    const int start = row_off[wid];
    const int dg    = deg[wid];

    // ---- pass 1: denominator ----
    float4 den = make_float4(0.f, 0.f, 0.f, 0.f);
    for (int i = lane; i < dg; i += 64) {
        float4 w = csr_w[start + i];
        den.x += w.x; den.y += w.y; den.z += w.z; den.w += w.w;
    }
#pragma unroll
    for (int off = 32; off > 0; off >>= 1) {
        den.x += __shfl_xor(den.x, off);
        den.y += __shfl_xor(den.y, off);
        den.z += __shfl_xor(den.z, off);
        den.w += __shfl_xor(den.w, off);
    }
    const int khead = lane >> 4;           // head owned by this lane
    float invk = khead == 0 ? den.x : khead == 1 ? den.y : khead == 2 ? den.z : den.w;
    invk = invk > 0.f ? 0.25f / invk : 0.f;

    // ---- pass 2: gather + accumulate ----
    const float* wf = (const float*)csr_w;
    float4 acc = make_float4(0.f, 0.f, 0.f, 0.f);
    for (int i = 0; i < dg; ++i) {
        int s    = csr_src[start + i];                               // broadcast
        float wk = wf[((size_t)(start + i) << 2) + khead] * invk;    // per-head
        float4 hv = *(const float4*)(hw + ((size_t)s << 8) + (lane << 2));
        acc.x += wk * hv.x; acc.y += wk * hv.y; acc.z += wk * hv.z; acc.w += wk * hv.w;
    }
    // reduce across the 4 head groups (lanes l, l^16, l^32 hold same j4)
#pragma unroll
    for (int off = 16; off < 64; off <<= 1) {
        acc.x += __shfl_xor(acc.x, off);
        acc.y += __shfl_xor(acc.y, off);
        acc.z += __shfl_xor(acc.z, off);
        acc.w += __shfl_xor(acc.w, off);
    }
    if (lane < 16) *(float4*)(out + (size_t)wid * OUT_DIM + (lane << 2)) = acc;
}

// ---------------------------------------------------------------------------
extern "C" void kernel_launch(void* const* d_in, const int* in_sizes, int n_in,
                              void* d_out, int out_size, void* d_ws, size_t ws_size,
                              hipStream_t stream) {
    const float* h     = (const float*)d_in[0];
    const int*   edges = (const int*)d_in[1];
    const float* W     = (const float*)d_in[2];
    const float* a     = (const float*)d_in[3];
    float* out = (float*)d_out;

    char* ws = (char*)d_ws;
    float*  hw      = (float*) (ws);                 // 102,400,000 B  [N][256] f32
    float*  sArr    = (float*) (ws + 102400000);     //   3,200,000 B
    float*  Wa      = (float*) (ws + 105600000);     //       4,096 B
    int*    deg     = (int*)   (ws + 105604096);     //     400,000 B
    int*    row_off = (int*)   (ws + 106004096);     //     400,000 B
    int*    cursor  = (int*)   (ws + 106404096);     //     400,000 B
    int*    partial = (int*)   (ws + 106804096);     //       4,096 B
    int*    csr_src = (int*)   (ws + 106808192);     //   6,400,000 B
    float4* csr_w   = (float4*)(ws + 113208192);     //  25,600,000 B   (total ~138.8 MB)

    const int NB_SCAN = (N_NODES + 1023) / 1024;     // 98

    hipMemsetAsync(deg, 0, (size_t)N_NODES * sizeof(int), stream);

    wa_kernel<<<4, 256, 0, stream>>>(W, a, Wa);
    s_kernel<<<(N_NODES + 255) / 256, 256, 0, stream>>>(h, Wa, sArr);
    gemm_kernel<<<dim3((N_NODES + 63) / 64, HEADS), 256, 0, stream>>>(h, W, hw);

    deg_hist<<<(N_EDGES + 255) / 256, 256, 0, stream>>>(edges, deg);
    deg_blocksum<<<NB_SCAN, 256, 0, stream>>>(deg, partial);
    scan_partials<<<1, 128, 0, stream>>>(partial, NB_SCAN);
    deg_scan_write<<<NB_SCAN, 256, 0, stream>>>(deg, partial, row_off, cursor);
    scatter_kernel<<<(N_EDGES + 255) / 256, 256, 0, stream>>>(edges, sArr, cursor, csr_src, csr_w);

    msg_csr<<<(N_NODES + 3) / 4, 256, 0, stream>>>(row_off, deg, csr_src, csr_w, hw, out);
}

// Round 3
// 385.486 us; speedup vs baseline: 2.2496x; 1.3609x over previous
//
#include <hip/hip_runtime.h>
#include <hip/hip_fp16.h>

#define N_NODES 100000
#define N_EDGES 1600000
#define IN_DIM  128
#define OUT_DIM 64
#define HEADS   4
#define SLOPE   0.2f
#define CLIP_LO 0.005f
#define CLIP_HI 10.0f

typedef short bf16x8 __attribute__((ext_vector_type(8)));
typedef float f32x4  __attribute__((ext_vector_type(4)));

__device__ __forceinline__ short f2bf(float x) {
    union { float f; unsigned u; } v; v.f = x;
    unsigned r = (v.u + 0x7FFF + ((v.u >> 16) & 1)) >> 16;   // RNE
    return (short)r;
}
__device__ __forceinline__ unsigned short f2hbits(float x) {
    union { __half h; unsigned short u; } c; c.h = __float2half(x); return c.u;
}
__device__ __forceinline__ float hbits2f(unsigned short b) {
    union { __half h; unsigned short u; } c; c.u = b; return __half2float(c.h);
}

// ---------------------------------------------------------------------------
// prep: WcatT[n][i] = bf16(W[k][i][j]) with n=k*64+j  (B matrix, [256][128])
//       Wa[k][half][i] = sum_j W[k][i][j]*a[k][half*64+j]
// ---------------------------------------------------------------------------
__global__ __launch_bounds__(256) void prep_kernel(const float* __restrict__ W,
                                                   const float* __restrict__ a,
                                                   short* __restrict__ WcatT,
                                                   float* __restrict__ Wa) {
    int idx = blockIdx.x * 256 + threadIdx.x;
    if (idx < 256 * 128) {
        int n = idx >> 7, i = idx & 127;
        int k = n >> 6, j = n & 63;
        WcatT[idx] = f2bf(W[((size_t)k * IN_DIM + i) * OUT_DIM + j]);
    } else if (idx < 256 * 128 + 1024) {
        int o = idx - 256 * 128;
        int k = o >> 8, half = (o >> 7) & 1, i = o & 127;
        const float* wrow = W + ((size_t)k * IN_DIM + i) * OUT_DIM;
        const float* av   = a + k * 2 * OUT_DIM + half * OUT_DIM;
        float acc = 0.f;
#pragma unroll 8
        for (int j = 0; j < OUT_DIM; ++j) acc += wrow[j] * av[j];
        Wa[o] = acc;
    }
}

// ---------------------------------------------------------------------------
// s_kernel: exact f32 scores via h @ Wa
// ---------------------------------------------------------------------------
__global__ __launch_bounds__(256) void s_kernel(const float* __restrict__ h,
                                                const float* __restrict__ Wa,
                                                float* __restrict__ sArr) {
    __shared__ __align__(16) float wa_s[HEADS * 2 * IN_DIM];
    for (int t = threadIdx.x; t < HEADS * 2 * IN_DIM; t += 256) wa_s[t] = Wa[t];
    __syncthreads();
    int n = blockIdx.x * 256 + threadIdx.x;
    if (n >= N_NODES) return;
    const float4* hv = (const float4*)(h + (size_t)n * IN_DIM);
    const float4* wv = (const float4*)wa_s;
    float acc[8] = {0.f,0.f,0.f,0.f,0.f,0.f,0.f,0.f};
    for (int i4 = 0; i4 < IN_DIM / 4; ++i4) {
        float4 hx = hv[i4];
#pragma unroll
        for (int k2 = 0; k2 < 8; ++k2) {
            float4 w = wv[k2 * (IN_DIM / 4) + i4];
            acc[k2] += hx.x * w.x + hx.y * w.y + hx.z * w.z + hx.w * w.w;
        }
    }
    float* o = sArr + (size_t)n * 8;
#pragma unroll
    for (int k = 0; k < 4; ++k) { o[k] = acc[2 * k]; o[4 + k] = acc[2 * k + 1]; }
}

// ---------------------------------------------------------------------------
// gemm_mfma: hw[n][k*64+j] (fp16, node-major [N][256]) = h @ Wcat  via bf16 MFMA
// BM=64 rows/block, 4 waves each own a 64-col stripe. K=128 in 4 steps of 32.
// ---------------------------------------------------------------------------
__global__ __launch_bounds__(256) void gemm_mfma(const float* __restrict__ h,
                                                 const short* __restrict__ WcatT,
                                                 __half* __restrict__ hw) {
    __shared__ __align__(16) short As[64][136];   // bf16, +8 pad (17.4KB)
    const int row0 = blockIdx.x * 64;
    const int tid  = threadIdx.x;

    // stage 64 rows of h as bf16
#pragma unroll
    for (int u = 0; u < 4; ++u) {
        int e = (tid + u * 256) * 8;          // 0..8191, step 8
        int r = e >> 7, c = e & 127;
        int grow = row0 + r; if (grow >= N_NODES) grow = N_NODES - 1;
        const float* hp = h + (size_t)grow * IN_DIM + c;
        float4 v0 = *(const float4*)hp;
        float4 v1 = *(const float4*)(hp + 4);
        bf16x8 b;
        b[0]=f2bf(v0.x); b[1]=f2bf(v0.y); b[2]=f2bf(v0.z); b[3]=f2bf(v0.w);
        b[4]=f2bf(v1.x); b[5]=f2bf(v1.y); b[6]=f2bf(v1.z); b[7]=f2bf(v1.w);
        *(bf16x8*)&As[r][c] = b;
    }
    __syncthreads();

    const int wv = tid >> 6, lane = tid & 63;
    const int lrow = lane & 15;
    const int lk   = (lane >> 4) * 8;

    // B fragments (WcatT rows are n, 128 bf16 each; L2-hot 64KB)
    bf16x8 bfr[4][4];
#pragma unroll
    for (int nt = 0; nt < 4; ++nt)
#pragma unroll
        for (int ks = 0; ks < 4; ++ks)
            bfr[nt][ks] = *(const bf16x8*)(WcatT + (size_t)(wv * 64 + nt * 16 + lrow) * 128 + ks * 32 + lk);

    f32x4 acc[4][4] = {};
#pragma unroll
    for (int ks = 0; ks < 4; ++ks) {
        bf16x8 afr[4];
#pragma unroll
        for (int mt = 0; mt < 4; ++mt)
            afr[mt] = *(const bf16x8*)&As[mt * 16 + lrow][ks * 32 + lk];
#pragma unroll
        for (int mt = 0; mt < 4; ++mt)
#pragma unroll
            for (int nt = 0; nt < 4; ++nt)
                acc[mt][nt] = __builtin_amdgcn_mfma_f32_16x16x32_bf16(afr[mt], bfr[nt][ks], acc[mt][nt], 0, 0, 0);
    }

    // C/D layout (m89-verified): col = lane&15, row = (lane>>4)*4 + reg
    const int rgrp = lane >> 4;
#pragma unroll
    for (int mt = 0; mt < 4; ++mt)
#pragma unroll
        for (int reg = 0; reg < 4; ++reg) {
            int m = row0 + mt * 16 + rgrp * 4 + reg;
            if (m < N_NODES) {
#pragma unroll
                for (int nt = 0; nt < 4; ++nt)
                    hw[(size_t)m * 256 + wv * 64 + nt * 16 + lrow] = __float2half(acc[mt][nt][reg]);
            }
        }
}

// ---------------------------------------------------------------------------
__device__ __forceinline__ float edge_e(float x) {
    x = x > 0.f ? x : SLOPE * x;
    float ev = __expf(x);
    return fminf(fmaxf(ev, CLIP_LO), CLIP_HI);
}

__global__ __launch_bounds__(256) void deg_hist(const int* __restrict__ edges,
                                                int* __restrict__ deg) {
    int e = blockIdx.x * 256 + threadIdx.x;
    if (e >= N_EDGES) return;
    atomicAdd(&deg[edges[N_EDGES + e]], 1);
}

__global__ __launch_bounds__(256) void deg_blocksum(const int* __restrict__ deg,
                                                    int* __restrict__ partial) {
    __shared__ int red[256];
    int base = blockIdx.x * 1024 + threadIdx.x * 4;
    int s = 0;
#pragma unroll
    for (int u = 0; u < 4; ++u) { int i = base + u; if (i < N_NODES) s += deg[i]; }
    red[threadIdx.x] = s; __syncthreads();
    for (int off = 128; off > 0; off >>= 1) {
        if (threadIdx.x < off) red[threadIdx.x] += red[threadIdx.x + off];
        __syncthreads();
    }
    if (threadIdx.x == 0) partial[blockIdx.x] = red[0];
}

__global__ __launch_bounds__(128) void scan_partials(int* __restrict__ partial, int nb) {
    __shared__ int sm[128];
    int t = threadIdx.x;
    sm[t] = (t < nb) ? partial[t] : 0;
    __syncthreads();
    if (t == 0) {
        int run = 0;
        for (int i = 0; i < nb; ++i) { int v = sm[i]; sm[i] = run; run += v; }
    }
    __syncthreads();
    if (t < nb) partial[t] = sm[t];
}

__global__ __launch_bounds__(256) void deg_scan_write(const int* __restrict__ deg,
                                                      const int* __restrict__ partial,
                                                      int* __restrict__ row_off,
                                                      int* __restrict__ cursor) {
    __shared__ int sc[2][256];
    int t = threadIdx.x;
    int base = blockIdx.x * 1024 + t * 4;
    int v[4]; int s = 0;
#pragma unroll
    for (int u = 0; u < 4; ++u) { int i = base + u; v[u] = (i < N_NODES) ? deg[i] : 0; s += v[u]; }
    sc[0][t] = s; __syncthreads();
    int cur = 0;
    for (int off = 1; off < 256; off <<= 1) {
        int x = sc[cur][t];
        if (t >= off) x += sc[cur][t - off];
        sc[cur ^ 1][t] = x; __syncthreads(); cur ^= 1;
    }
    int excl = sc[cur][t] - s;
    int run = partial[blockIdx.x] + excl;
#pragma unroll
    for (int u = 0; u < 4; ++u) {
        int i = base + u;
        if (i < N_NODES) { row_off[i] = run; cursor[i] = run; run += v[u]; }
    }
}

// scatter: one 16B record per edge {src, half w0..w3}
__global__ __launch_bounds__(256) void scatter_kernel(const int* __restrict__ edges,
                                                      const float* __restrict__ sArr,
                                                      int* __restrict__ cursor,
                                                      uint4* __restrict__ csr) {
    int e = blockIdx.x * 256 + threadIdx.x;
    if (e >= N_EDGES) return;
    int s = edges[e], d = edges[N_EDGES + e];
    float4 ss = *(const float4*)(sArr + (size_t)s * 8);
    float4 sd = *(const float4*)(sArr + (size_t)d * 8 + 4);
    unsigned w0 = f2hbits(edge_e(ss.x + sd.x));
    unsigned w1 = f2hbits(edge_e(ss.y + sd.y));
    unsigned w2 = f2hbits(edge_e(ss.z + sd.z));
    unsigned w3 = f2hbits(edge_e(ss.w + sd.w));
    uint4 rec;
    rec.x = (unsigned)s;
    rec.y = w0 | (w1 << 16);
    rec.z = w2 | (w3 << 16);
    rec.w = 0;
    int pos = atomicAdd(&cursor[d], 1);
    csr[pos] = rec;
}

// ---------------------------------------------------------------------------
// msg_csr: one wave per dst. Pass1 denom from records; pass2 fp16 hw gather
// (64 lanes x 8B = whole 512B node row), cross-head reduce, one store.
// ---------------------------------------------------------------------------
__global__ __launch_bounds__(256) void msg_csr(const int* __restrict__ row_off,
                                               const int* __restrict__ deg,
                                               const uint4* __restrict__ csr,
                                               const __half* __restrict__ hw,
                                               float* __restrict__ out) {
    int wid  = (blockIdx.x * 256 + threadIdx.x) >> 6;
    int lane = threadIdx.x & 63;
    if (wid >= N_NODES) return;
    const int start = row_off[wid];
    const int dg    = deg[wid];

    // pass 1: denominators
    float4 den = make_float4(0.f, 0.f, 0.f, 0.f);
    for (int i = lane; i < dg; i += 64) {
        uint4 rec = csr[start + i];
        den.x += hbits2f((unsigned short)(rec.y & 0xffff));
        den.y += hbits2f((unsigned short)(rec.y >> 16));
        den.z += hbits2f((unsigned short)(rec.z & 0xffff));
        den.w += hbits2f((unsigned short)(rec.z >> 16));
    }
#pragma unroll
    for (int off = 32; off > 0; off >>= 1) {
        den.x += __shfl_xor(den.x, off);
        den.y += __shfl_xor(den.y, off);
        den.z += __shfl_xor(den.z, off);
        den.w += __shfl_xor(den.w, off);
    }
    const int kh = lane >> 4;
    float invk = kh == 0 ? den.x : kh == 1 ? den.y : kh == 2 ? den.z : den.w;
    invk = invk > 0.f ? 0.25f / invk : 0.f;

    // pass 2: gather + accumulate
    float4 acc = make_float4(0.f, 0.f, 0.f, 0.f);
    for (int i = 0; i < dg; ++i) {
        uint4 rec = csr[start + i];                       // wave-uniform, L1-hot
        unsigned wp = (kh & 2) ? rec.z : rec.y;
        float wk = hbits2f((unsigned short)((kh & 1) ? (wp >> 16) : (wp & 0xffff))) * invk;
        const __half2* hp = (const __half2*)(hw + ((size_t)rec.x << 8) + (lane << 2));
        __half2 a0 = hp[0], a1 = hp[1];
        float2 f0 = __half22float2(a0), f1 = __half22float2(a1);
        acc.x += wk * f0.x; acc.y += wk * f0.y;
        acc.z += wk * f1.x; acc.w += wk * f1.y;
    }
#pragma unroll
    for (int off = 16; off < 64; off <<= 1) {
        acc.x += __shfl_xor(acc.x, off);
        acc.y += __shfl_xor(acc.y, off);
        acc.z += __shfl_xor(acc.z, off);
        acc.w += __shfl_xor(acc.w, off);
    }
    if (lane < 16) *(float4*)(out + (size_t)wid * OUT_DIM + (lane << 2)) =
        make_float4(acc.x, acc.y, acc.z, acc.w);
}

// ---------------------------------------------------------------------------
extern "C" void kernel_launch(void* const* d_in, const int* in_sizes, int n_in,
                              void* d_out, int out_size, void* d_ws, size_t ws_size,
                              hipStream_t stream) {
    const float* h     = (const float*)d_in[0];
    const int*   edges = (const int*)d_in[1];
    const float* W     = (const float*)d_in[2];
    const float* a     = (const float*)d_in[3];
    float* out = (float*)d_out;

    char* ws = (char*)d_ws;
    __half* hw      = (__half*)(ws);                    // 51,200,000 B  [N][256] f16
    float*  sArr    = (float*) (ws + 51200000);         //  3,200,000 B
    float*  Wa      = (float*) (ws + 54400000);         //      4,096 B
    short*  WcatT   = (short*) (ws + 54404096);         //     65,536 B
    int*    deg     = (int*)   (ws + 54469632);         //    400,000 B
    int*    row_off = (int*)   (ws + 54869632);         //    400,000 B
    int*    cursor  = (int*)   (ws + 55269632);         //    400,000 B
    int*    partial = (int*)   (ws + 55669632);         //      4,096 B
    uint4*  csr     = (uint4*) (ws + 55673728);         // 25,600,000 B  (~81.3 MB total)

    const int NB_SCAN = (N_NODES + 1023) / 1024;        // 98

    hipMemsetAsync(deg, 0, (size_t)N_NODES * sizeof(int), stream);

    prep_kernel<<<132, 256, 0, stream>>>(W, a, WcatT, Wa);
    s_kernel<<<(N_NODES + 255) / 256, 256, 0, stream>>>(h, Wa, sArr);
    gemm_mfma<<<(N_NODES + 63) / 64, 256, 0, stream>>>(h, WcatT, hw);

    deg_hist<<<(N_EDGES + 255) / 256, 256, 0, stream>>>(edges, deg);
    deg_blocksum<<<NB_SCAN, 256, 0, stream>>>(deg, partial);
    scan_partials<<<1, 128, 0, stream>>>(partial, NB_SCAN);
    deg_scan_write<<<NB_SCAN, 256, 0, stream>>>(deg, partial, row_off, cursor);
    scatter_kernel<<<(N_EDGES + 255) / 256, 256, 0, stream>>>(edges, sArr, cursor, csr);

    msg_csr<<<(N_NODES + 3) / 4, 256, 0, stream>>>(row_off, deg, csr, hw, out);
}

// Round 4
// 329.345 us; speedup vs baseline: 2.6331x; 1.1705x over previous
//
#include <hip/hip_runtime.h>
#include <hip/hip_fp16.h>

#define N_NODES 100000
#define N_EDGES 1600000
#define IN_DIM  128
#define OUT_DIM 64
#define HEADS   4
#define SLOPE   0.2f
#define CLIP_LO 0.005f
#define CLIP_HI 10.0f

typedef short bf16x8 __attribute__((ext_vector_type(8)));
typedef float f32x4  __attribute__((ext_vector_type(4)));

__device__ __forceinline__ short f2bf(float x) {
    union { float f; unsigned u; } v; v.f = x;
    unsigned r = (v.u + 0x7FFF + ((v.u >> 16) & 1)) >> 16;   // RNE
    return (short)r;
}
__device__ __forceinline__ unsigned short f2hbits(float x) {
    union { __half h; unsigned short u; } c; c.h = __float2half(x); return c.u;
}
__device__ __forceinline__ float hbits2f(unsigned short b) {
    union { __half h; unsigned short u; } c; c.u = b; return __half2float(c.h);
}

// ---------------------------------------------------------------------------
// prep: WcatT[n][i] = bf16(W[k][i][j]) with n=k*64+j  (B matrix, [256][128])
//       Wa[k][half][i] = sum_j W[k][i][j]*a[k][half*64+j]
// ---------------------------------------------------------------------------
__global__ __launch_bounds__(256) void prep_kernel(const float* __restrict__ W,
                                                   const float* __restrict__ a,
                                                   short* __restrict__ WcatT,
                                                   float* __restrict__ Wa) {
    int idx = blockIdx.x * 256 + threadIdx.x;
    if (idx < 256 * 128) {
        int n = idx >> 7, i = idx & 127;
        int k = n >> 6, j = n & 63;
        WcatT[idx] = f2bf(W[((size_t)k * IN_DIM + i) * OUT_DIM + j]);
    } else if (idx < 256 * 128 + 1024) {
        int o = idx - 256 * 128;
        int k = o >> 8, half = (o >> 7) & 1, i = o & 127;
        const float* wrow = W + ((size_t)k * IN_DIM + i) * OUT_DIM;
        const float* av   = a + k * 2 * OUT_DIM + half * OUT_DIM;
        float acc = 0.f;
#pragma unroll 8
        for (int j = 0; j < OUT_DIM; ++j) acc += wrow[j] * av[j];
        Wa[o] = acc;
    }
}

// ---------------------------------------------------------------------------
// s_kernel: exact f32 scores via h @ Wa
// ---------------------------------------------------------------------------
__global__ __launch_bounds__(256) void s_kernel(const float* __restrict__ h,
                                                const float* __restrict__ Wa,
                                                float* __restrict__ sArr) {
    __shared__ __align__(16) float wa_s[HEADS * 2 * IN_DIM];
    for (int t = threadIdx.x; t < HEADS * 2 * IN_DIM; t += 256) wa_s[t] = Wa[t];
    __syncthreads();
    int n = blockIdx.x * 256 + threadIdx.x;
    if (n >= N_NODES) return;
    const float4* hv = (const float4*)(h + (size_t)n * IN_DIM);
    const float4* wv = (const float4*)wa_s;
    float acc[8] = {0.f,0.f,0.f,0.f,0.f,0.f,0.f,0.f};
    for (int i4 = 0; i4 < IN_DIM / 4; ++i4) {
        float4 hx = hv[i4];
#pragma unroll
        for (int k2 = 0; k2 < 8; ++k2) {
            float4 w = wv[k2 * (IN_DIM / 4) + i4];
            acc[k2] += hx.x * w.x + hx.y * w.y + hx.z * w.z + hx.w * w.w;
        }
    }
    float* o = sArr + (size_t)n * 8;
#pragma unroll
    for (int k = 0; k < 4; ++k) { o[k] = acc[2 * k]; o[4 + k] = acc[2 * k + 1]; }
}

// ---------------------------------------------------------------------------
// gemm_mfma: hw[n][k*64+j] (fp16, node-major [N][256]) = h @ Wcat via bf16 MFMA
// Epilogue staged through LDS for coalesced dwordx4 stores.
// ---------------------------------------------------------------------------
__global__ __launch_bounds__(256) void gemm_mfma(const float* __restrict__ h,
                                                 const short* __restrict__ WcatT,
                                                 __half* __restrict__ hw) {
    __shared__ __align__(16) short As[64][136];            // 17.4KB
    __shared__ __align__(16) unsigned short Cs[64][264];   // 33.8KB (+8 pad)
    const int row0 = blockIdx.x * 64;
    const int tid  = threadIdx.x;

#pragma unroll
    for (int u = 0; u < 4; ++u) {
        int e = (tid + u * 256) * 8;
        int r = e >> 7, c = e & 127;
        int grow = row0 + r; if (grow >= N_NODES) grow = N_NODES - 1;
        const float* hp = h + (size_t)grow * IN_DIM + c;
        float4 v0 = *(const float4*)hp;
        float4 v1 = *(const float4*)(hp + 4);
        bf16x8 b;
        b[0]=f2bf(v0.x); b[1]=f2bf(v0.y); b[2]=f2bf(v0.z); b[3]=f2bf(v0.w);
        b[4]=f2bf(v1.x); b[5]=f2bf(v1.y); b[6]=f2bf(v1.z); b[7]=f2bf(v1.w);
        *(bf16x8*)&As[r][c] = b;
    }
    __syncthreads();

    const int wv = tid >> 6, lane = tid & 63;
    const int lrow = lane & 15;
    const int lk   = (lane >> 4) * 8;

    bf16x8 bfr[4][4];
#pragma unroll
    for (int nt = 0; nt < 4; ++nt)
#pragma unroll
        for (int ks = 0; ks < 4; ++ks)
            bfr[nt][ks] = *(const bf16x8*)(WcatT + (size_t)(wv * 64 + nt * 16 + lrow) * 128 + ks * 32 + lk);

    f32x4 acc[4][4] = {};
#pragma unroll
    for (int ks = 0; ks < 4; ++ks) {
        bf16x8 afr[4];
#pragma unroll
        for (int mt = 0; mt < 4; ++mt)
            afr[mt] = *(const bf16x8*)&As[mt * 16 + lrow][ks * 32 + lk];
#pragma unroll
        for (int mt = 0; mt < 4; ++mt)
#pragma unroll
            for (int nt = 0; nt < 4; ++nt)
                acc[mt][nt] = __builtin_amdgcn_mfma_f32_16x16x32_bf16(afr[mt], bfr[nt][ks], acc[mt][nt], 0, 0, 0);
    }

    // stage C into LDS (C/D layout: col=lane&15, row=(lane>>4)*4+reg)
    const int rgrp = lane >> 4;
#pragma unroll
    for (int mt = 0; mt < 4; ++mt)
#pragma unroll
        for (int reg = 0; reg < 4; ++reg) {
            int r = mt * 16 + rgrp * 4 + reg;
#pragma unroll
            for (int nt = 0; nt < 4; ++nt)
                Cs[r][wv * 64 + nt * 16 + lrow] = f2hbits(acc[mt][nt][reg]);
        }
    __syncthreads();

    // coalesced writeout: thread t -> row t>>2, 64 halfs (128B)
    {
        const int r  = tid >> 2;
        const int c0 = (tid & 3) * 64;
        int g = row0 + r;
        if (g < N_NODES) {
            const uint4* src = (const uint4*)&Cs[r][c0];
            uint4* dst = (uint4*)(hw + (size_t)g * 256 + c0);
#pragma unroll
            for (int u = 0; u < 8; ++u) dst[u] = src[u];
        }
    }
}

// ---------------------------------------------------------------------------
__device__ __forceinline__ float edge_e(float x) {
    x = x > 0.f ? x : SLOPE * x;
    float ev = __expf(x);
    return fminf(fmaxf(ev, CLIP_LO), CLIP_HI);
}

__global__ __launch_bounds__(256) void deg_hist(const int* __restrict__ edges,
                                                int* __restrict__ deg) {
    int e = blockIdx.x * 256 + threadIdx.x;
    if (e >= N_EDGES) return;
    atomicAdd(&deg[edges[N_EDGES + e]], 1);
}

__global__ __launch_bounds__(256) void deg_blocksum(const int* __restrict__ deg,
                                                    int* __restrict__ partial) {
    __shared__ int red[256];
    int base = blockIdx.x * 1024 + threadIdx.x * 4;
    int s = 0;
#pragma unroll
    for (int u = 0; u < 4; ++u) { int i = base + u; if (i < N_NODES) s += deg[i]; }
    red[threadIdx.x] = s; __syncthreads();
    for (int off = 128; off > 0; off >>= 1) {
        if (threadIdx.x < off) red[threadIdx.x] += red[threadIdx.x + off];
        __syncthreads();
    }
    if (threadIdx.x == 0) partial[blockIdx.x] = red[0];
}

__global__ __launch_bounds__(128) void scan_partials(int* __restrict__ partial, int nb) {
    __shared__ int sm[128];
    int t = threadIdx.x;
    sm[t] = (t < nb) ? partial[t] : 0;
    __syncthreads();
    if (t == 0) {
        int run = 0;
        for (int i = 0; i < nb; ++i) { int v = sm[i]; sm[i] = run; run += v; }
    }
    __syncthreads();
    if (t < nb) partial[t] = sm[t];
}

__global__ __launch_bounds__(256) void deg_scan_write(const int* __restrict__ deg,
                                                      const int* __restrict__ partial,
                                                      int* __restrict__ row_off,
                                                      int* __restrict__ cursor) {
    __shared__ int sc[2][256];
    int t = threadIdx.x;
    int base = blockIdx.x * 1024 + t * 4;
    int v[4]; int s = 0;
#pragma unroll
    for (int u = 0; u < 4; ++u) { int i = base + u; v[u] = (i < N_NODES) ? deg[i] : 0; s += v[u]; }
    sc[0][t] = s; __syncthreads();
    int cur = 0;
    for (int off = 1; off < 256; off <<= 1) {
        int x = sc[cur][t];
        if (t >= off) x += sc[cur][t - off];
        sc[cur ^ 1][t] = x; __syncthreads(); cur ^= 1;
    }
    int excl = sc[cur][t] - s;
    int run = partial[blockIdx.x] + excl;
#pragma unroll
    for (int u = 0; u < 4; ++u) {
        int i = base + u;
        if (i < N_NODES) { row_off[i] = run; cursor[i] = run; run += v[u]; }
    }
}

__global__ __launch_bounds__(256) void scatter_kernel(const int* __restrict__ edges,
                                                      const float* __restrict__ sArr,
                                                      int* __restrict__ cursor,
                                                      uint4* __restrict__ csr) {
    int e = blockIdx.x * 256 + threadIdx.x;
    if (e >= N_EDGES) return;
    int s = edges[e], d = edges[N_EDGES + e];
    float4 ss = *(const float4*)(sArr + (size_t)s * 8);
    float4 sd = *(const float4*)(sArr + (size_t)d * 8 + 4);
    unsigned w0 = f2hbits(edge_e(ss.x + sd.x));
    unsigned w1 = f2hbits(edge_e(ss.y + sd.y));
    unsigned w2 = f2hbits(edge_e(ss.z + sd.z));
    unsigned w3 = f2hbits(edge_e(ss.w + sd.w));
    uint4 rec;
    rec.x = (unsigned)s;
    rec.y = w0 | (w1 << 16);
    rec.z = w2 | (w3 << 16);
    rec.w = 0;
    int pos = atomicAdd(&cursor[d], 1);
    csr[pos] = rec;
}

// ---------------------------------------------------------------------------
__device__ __forceinline__ float pickw(const uint4& r, int kh) {
    unsigned wp = (kh & 2) ? r.z : r.y;
    return hbits2f((unsigned short)((kh & 1) ? (wp >> 16) : (wp & 0xffff)));
}
__device__ __forceinline__ void fmacc(float4& a, uint2 g, float w) {
    __half2 h0 = *(__half2*)&g.x, h1 = *(__half2*)&g.y;
    float2 f0 = __half22float2(h0), f1 = __half22float2(h1);
    a.x += w * f0.x; a.y += w * f0.y; a.z += w * f1.x; a.w += w * f1.y;
}

// msg_csr: one wave per dst; pass2 hand-unrolled x4 for MLP
__global__ __launch_bounds__(256) void msg_csr(const int* __restrict__ row_off,
                                               const int* __restrict__ deg,
                                               const uint4* __restrict__ csr,
                                               const __half* __restrict__ hw,
                                               float* __restrict__ out) {
    int wid  = (blockIdx.x * 256 + threadIdx.x) >> 6;
    int lane = threadIdx.x & 63;
    if (wid >= N_NODES) return;
    const int start = row_off[wid];
    const int dg    = deg[wid];

    // pass 1: denominators
    float4 den = make_float4(0.f, 0.f, 0.f, 0.f);
    for (int i = lane; i < dg; i += 64) {
        uint4 rec = csr[start + i];
        den.x += hbits2f((unsigned short)(rec.y & 0xffff));
        den.y += hbits2f((unsigned short)(rec.y >> 16));
        den.z += hbits2f((unsigned short)(rec.z & 0xffff));
        den.w += hbits2f((unsigned short)(rec.z >> 16));
    }
#pragma unroll
    for (int off = 32; off > 0; off >>= 1) {
        den.x += __shfl_xor(den.x, off);
        den.y += __shfl_xor(den.y, off);
        den.z += __shfl_xor(den.z, off);
        den.w += __shfl_xor(den.w, off);
    }
    const int kh = lane >> 4;
    float invk = kh == 0 ? den.x : kh == 1 ? den.y : kh == 2 ? den.z : den.w;
    invk = invk > 0.f ? 0.25f / invk : 0.f;

    // pass 2: gather + accumulate, 4 edges in flight
    const size_t loff = (size_t)(lane << 2);
    float4 acc = make_float4(0.f, 0.f, 0.f, 0.f);
    int i = 0;
    for (; i + 4 <= dg; i += 4) {
        uint4 r0 = csr[start + i];
        uint4 r1 = csr[start + i + 1];
        uint4 r2 = csr[start + i + 2];
        uint4 r3 = csr[start + i + 3];
        uint2 g0 = *(const uint2*)(hw + (((size_t)r0.x) << 8) + loff);
        uint2 g1 = *(const uint2*)(hw + (((size_t)r1.x) << 8) + loff);
        uint2 g2 = *(const uint2*)(hw + (((size_t)r2.x) << 8) + loff);
        uint2 g3 = *(const uint2*)(hw + (((size_t)r3.x) << 8) + loff);
        float w0 = pickw(r0, kh) * invk;
        float w1 = pickw(r1, kh) * invk;
        float w2 = pickw(r2, kh) * invk;
        float w3 = pickw(r3, kh) * invk;
        fmacc(acc, g0, w0);
        fmacc(acc, g1, w1);
        fmacc(acc, g2, w2);
        fmacc(acc, g3, w3);
    }
    for (; i < dg; ++i) {
        uint4 r = csr[start + i];
        uint2 g = *(const uint2*)(hw + (((size_t)r.x) << 8) + loff);
        fmacc(acc, g, pickw(r, kh) * invk);
    }

#pragma unroll
    for (int off = 16; off < 64; off <<= 1) {
        acc.x += __shfl_xor(acc.x, off);
        acc.y += __shfl_xor(acc.y, off);
        acc.z += __shfl_xor(acc.z, off);
        acc.w += __shfl_xor(acc.w, off);
    }
    if (lane < 16) *(float4*)(out + (size_t)wid * OUT_DIM + (lane << 2)) =
        make_float4(acc.x, acc.y, acc.z, acc.w);
}

// ---------------------------------------------------------------------------
extern "C" void kernel_launch(void* const* d_in, const int* in_sizes, int n_in,
                              void* d_out, int out_size, void* d_ws, size_t ws_size,
                              hipStream_t stream) {
    const float* h     = (const float*)d_in[0];
    const int*   edges = (const int*)d_in[1];
    const float* W     = (const float*)d_in[2];
    const float* a     = (const float*)d_in[3];
    float* out = (float*)d_out;

    char* ws = (char*)d_ws;
    __half* hw      = (__half*)(ws);                    // 51,200,000 B  [N][256] f16
    float*  sArr    = (float*) (ws + 51200000);         //  3,200,000 B
    float*  Wa      = (float*) (ws + 54400000);         //      4,096 B
    short*  WcatT   = (short*) (ws + 54404096);         //     65,536 B
    int*    deg     = (int*)   (ws + 54469632);         //    400,000 B
    int*    row_off = (int*)   (ws + 54869632);         //    400,000 B
    int*    cursor  = (int*)   (ws + 55269632);         //    400,000 B
    int*    partial = (int*)   (ws + 55669632);         //      4,096 B
    uint4*  csr     = (uint4*) (ws + 55673728);         // 25,600,000 B

    const int NB_SCAN = (N_NODES + 1023) / 1024;        // 98

    hipMemsetAsync(deg, 0, (size_t)N_NODES * sizeof(int), stream);

    prep_kernel<<<132, 256, 0, stream>>>(W, a, WcatT, Wa);
    s_kernel<<<(N_NODES + 255) / 256, 256, 0, stream>>>(h, Wa, sArr);
    gemm_mfma<<<(N_NODES + 63) / 64, 256, 0, stream>>>(h, WcatT, hw);

    deg_hist<<<(N_EDGES + 255) / 256, 256, 0, stream>>>(edges, deg);
    deg_blocksum<<<NB_SCAN, 256, 0, stream>>>(deg, partial);
    scan_partials<<<1, 128, 0, stream>>>(partial, NB_SCAN);
    deg_scan_write<<<NB_SCAN, 256, 0, stream>>>(deg, partial, row_off, cursor);
    scatter_kernel<<<(N_EDGES + 255) / 256, 256, 0, stream>>>(edges, sArr, cursor, csr);

    msg_csr<<<(N_NODES + 3) / 4, 256, 0, stream>>>(row_off, deg, csr, hw, out);
}